// Round 7
// baseline (343.862 us; speedup 1.0000x reference)
//
#include <hip/hip_runtime.h>
#include <math.h>

#define B_   128
#define N_   1024
#define D_   256
#define G_   64
#define GSZ_ 3
#define RD_  16
#define KD_  64
#define PD_  64
#define NF_  64
#define Q_   (G_*GSZ_)   // 192

typedef __attribute__((ext_vector_type(8))) short bf16x8;   // 8 bf16 = 4 VGPRs
typedef __attribute__((ext_vector_type(4))) float f32x4;

__device__ __forceinline__ unsigned short f2bf(float f) {
    unsigned int u = __float_as_uint(f);
    u += 0x7fffu + ((u >> 16) & 1u);       // RNE
    return (unsigned short)(u >> 16);
}

// ---------------------------------------------------------------------------
// coef_kernel: S3-symmetrized filter has 2 DOF per (f,r) (diag / off-diag
// orbit). out = sum_r c1[f,r]*T1[r] + c2[f,r]*T2[r].
// ---------------------------------------------------------------------------
__global__ void coef_kernel(const float* __restrict__ filters,
                            float* __restrict__ coef) {
    int flat = blockIdx.x * 256 + threadIdx.x;
    if (flat >= NF_ * RD_) return;
    int f = flat >> 4, r = flat & 15;
    const float* F = filters + f * 144 + r;
    float diag = F[0] + F[48 + 16] + F[96 + 32];
    float all = 0.f;
#pragma unroll
    for (int u = 0; u < 3; ++u)
#pragma unroll
        for (int v = 0; v < 3; ++v) all += F[u * 48 + v * 16];
    float a = diag * (1.f / 3.f);
    float b = (all - diag) * (1.f / 6.f);
    coef[f * 16 + r] = a - b;
    coef[1024 + f * 16 + r] = b;
}

// ---------------------------------------------------------------------------
// wb2: coalesced layout Wb[qk][r][kk(8)][p(64)][32d] bf16 (verified rel9/
// rel10: -20us on rel). Wave B-frag load = contiguous 1KB burst.
// ---------------------------------------------------------------------------
__global__ __launch_bounds__(256)
void wb2_kernel(const float* __restrict__ Wq,
                const float* __restrict__ Wk,
                unsigned short* __restrict__ Wb) {
    __shared__ unsigned short wt[64 * 264];
    int qk = blockIdx.x >> 4, r = blockIdx.x & 15;
    const float* W = qk ? Wk : Wq;
    int t = threadIdx.x;
#pragma unroll
    for (int i = 0; i < 16; ++i) {
        int flat = i * 256 + t;            // 4096: 256 d x 16 p4
        int d = flat >> 4, p4 = flat & 15;
        float4 v = *(const float4*)(W + ((size_t)r * 256 + d) * 64 + p4 * 4);
        wt[(p4 * 4 + 0) * 264 + d] = f2bf(v.x);
        wt[(p4 * 4 + 1) * 264 + d] = f2bf(v.y);
        wt[(p4 * 4 + 2) * 264 + d] = f2bf(v.z);
        wt[(p4 * 4 + 3) * 264 + d] = f2bf(v.w);
    }
    __syncthreads();
    size_t base = (size_t)(qk * 16 + r) * 16384;
#pragma unroll
    for (int i = 0; i < 8; ++i) {
        int flat = i * 256 + t;            // 2048 uint4: 64 p x 32 segs
        int p = flat >> 5, seg = flat & 31;
        // element (p, d = seg*8) -> [kk = seg>>2][p][d32 = (seg&3)*8]
        *(uint4*)(Wb + base + (size_t)(seg >> 2) * 2048 + p * 32 + (seg & 3) * 8) =
            *(const uint4*)(&wt[p * 264 + seg * 8]);
    }
}

// ---------------------------------------------------------------------------
// qeb_kernel: qeb = bf16(query_emb * beta), beta = 0.125 (exact pow2 scale)
// ---------------------------------------------------------------------------
__global__ void qeb_kernel(const float* __restrict__ qe,
                           unsigned short* __restrict__ qeb) {
    int i = blockIdx.x * 256 + threadIdx.x;
    if (i < Q_ * KD_) qeb[i] = f2bf(qe[i] * 0.125f);
}

// ---------------------------------------------------------------------------
// wkt_kernel: WkTb[kd][d] = bf16(Wk_map[d][kd])  (one-time, 16K elems)
// ---------------------------------------------------------------------------
__global__ void wkt_kernel(const float* __restrict__ Wk_map,
                           unsigned short* __restrict__ WkTb) {
    int i = blockIdx.x * 256 + threadIdx.x;   // [0, 16384)
    int kd = i >> 8, d = i & 255;
    WkTb[kd * 256 + d] = f2bf(Wk_map[d * 64 + kd]);
}

// ---------------------------------------------------------------------------
// xt_kernel: NEW OUTPUT LAYOUT (attn-fragment-contiguous).
// xtf[b][dt(16)][c(8)][ks(4)][lcol(16)][32] where d = dt*16+lcol and
// n = c*128 + ks*32 + (elem&31). A wave's PV B-frag load for one
// (dt,c,ks) is a contiguous 1KB burst instead of 16 lines at 2KB stride
// (rel4->rel10 lesson: ~4cy per discontiguous 64B line per load instr).
// ---------------------------------------------------------------------------
__global__ __launch_bounds__(256)
void xt_kernel(const float* __restrict__ x,
               unsigned short* __restrict__ xtf) {
    __shared__ float xs[128][65];
    int b = blockIdx.z, d0 = blockIdx.y * 64, n0 = blockIdx.x * 128;
    int c = blockIdx.x;                      // 128 n per block = one c slot
    int t = threadIdx.x;
#pragma unroll
    for (int i = 0; i < 8; ++i) {
        int f = i * 256 + t;
        int row = f >> 4, c4 = f & 15;       // 128 n-rows x 16 float4
        float4 v = *(const float4*)(x + ((size_t)b * N_ + n0 + row) * D_ + d0 + c4 * 4);
        xs[row][c4 * 4 + 0] = v.x; xs[row][c4 * 4 + 1] = v.y;
        xs[row][c4 * 4 + 2] = v.z; xs[row][c4 * 4 + 3] = v.w;
    }
    __syncthreads();
#pragma unroll
    for (int i = 0; i < 4; ++i) {
        int f = i * 256 + t;
        int dr = f >> 4, seg = f & 15;       // 64 d-rows x 16 n-chunks of 8
        uint4 uv;
        unsigned int* up = (unsigned int*)&uv;
#pragma unroll
        for (int j = 0; j < 4; ++j) {
            unsigned int lo = f2bf(xs[seg * 8 + 2 * j][dr]);
            unsigned int hi = f2bf(xs[seg * 8 + 2 * j + 1][dr]);
            up[j] = lo | (hi << 16);
        }
        int d = d0 + dr;
        int dt = d >> 4, lcol = d & 15;
        int ks = seg >> 2, quad = seg & 3;
        *(uint4*)(xtf + ((size_t)(((b * 16 + dt) * 8 + c) * 4 + ks) * 16 + lcol) * 32 + quad * 8) = uv;
    }
}

// ---------------------------------------------------------------------------
// kproj2: k = x@Wk_map + PE. NEW OUTPUT LAYOUT (attn-fragment-contiguous):
// kbf[b][ntile(64)][ks(2)][lcol(16)][32] where n = ntile*16+lcol and
// kd = ks*32 + (elem&31). S-phase B-frag load = contiguous 1KB burst
// instead of 16 lines at 128B stride.
// ---------------------------------------------------------------------------
#define WKP 264   // 256+8 bf16 pad, 16B-aligned rows

__global__ __launch_bounds__(256, 2)
void kproj2_kernel(const float* __restrict__ x,
                   const unsigned short* __restrict__ WkTb,
                   unsigned short* __restrict__ kbf) {
    __shared__ unsigned short wkts[64 * WKP];
    __shared__ unsigned short xs[64 * WKP];
    __shared__ unsigned short Ks[64 * 72];
    int b = blockIdx.y, n0 = blockIdx.x * 64;
    int t = threadIdx.x, w = t >> 6, lane = t & 63;
    int quad = lane >> 4, lcol = lane & 15;

#pragma unroll
    for (int i = 0; i < 8; ++i) {
        int f = i * 256 + t;
        int row = f >> 5, seg = f & 31;
        *(uint4*)(&wkts[row * WKP + seg * 8]) = *(const uint4*)(WkTb + row * 256 + seg * 8);
    }
#pragma unroll
    for (int i = 0; i < 16; ++i) {
        int f = i * 256 + t;
        int row = f >> 6, c4 = f & 63;
        float4 v = *(const float4*)(x + ((size_t)b * N_ + n0 + row) * D_ + c4 * 4);
        uint2 uv;
        uv.x = (unsigned int)f2bf(v.x) | ((unsigned int)f2bf(v.y) << 16);
        uv.y = (unsigned int)f2bf(v.z) | ((unsigned int)f2bf(v.w) << 16);
        *(uint2*)(&xs[row * WKP + c4 * 4]) = uv;
    }
    __syncthreads();

    f32x4 z[4];
#pragma unroll
    for (int mt = 0; mt < 4; ++mt) z[mt] = (f32x4)(0.f);
#pragma unroll
    for (int kk = 0; kk < 8; ++kk) {
        bf16x8 bf = *(const bf16x8*)(&xs[(w * 16 + lcol) * WKP + kk * 32 + quad * 8]);
#pragma unroll
        for (int mt = 0; mt < 4; ++mt) {
            bf16x8 af = *(const bf16x8*)(&wkts[(mt * 16 + lcol) * WKP + kk * 32 + quad * 8]);
            z[mt] = __builtin_amdgcn_mfma_f32_16x16x32_bf16(af, bf, z[mt], 0, 0, 0);
        }
    }

    int nl = w * 16 + lcol;
    int n = n0 + nl;
#pragma unroll
    for (int mt = 0; mt < 4; ++mt)
#pragma unroll
        for (int r = 0; r < 4; ++r) {
            int kd = mt * 16 + quad * 4 + r;
            float freq  = expf(-(float)(kd >> 1) * (logf(10000.0f) / 32.0f));
            float angle = (float)n * freq;
            float pe    = (kd & 1) ? cosf(angle) : sinf(angle);
            Ks[nl * 72 + kd] = f2bf(z[mt][r] + pe);
        }
    __syncthreads();

#pragma unroll
    for (int i = 0; i < 2; ++i) {
        int f = i * 256 + t;
        int row = f >> 3, seg = f & 7;       // 64 n-rows x 8 kd-chunks of 8
        int ntile = (n0 >> 4) + (row >> 4), lc = row & 15;
        int ks = seg >> 2, quad8 = (seg & 3) * 8;
        *(uint4*)(kbf + ((size_t)(b * 64 + ntile) * 2 + ks) * 512 + lc * 32 + quad8) =
            *(const uint4*)(&Ks[row * 72 + seg * 8]);
    }
}

// ---------------------------------------------------------------------------
// attn5: attn4 with both B-operand streams read from the new fragment-
// contiguous layouts (kbf, xtf). Per-lane data is identical to attn4; only
// addresses change -> every S and PV B-frag load is a contiguous 1KB
// burst. attn4 had 80 scattered loads/wave/block x 16 lines each (lcol
// stride 128B / 2KB) -- the same pathology that cost rel4 50us.
// ---------------------------------------------------------------------------
#define PSP2 136   // 128+8

__global__ __launch_bounds__(512, 2)
void attn5_kernel(const unsigned short* __restrict__ qeb,
                  const unsigned short* __restrict__ kbf,
                  const unsigned short* __restrict__ xtf,
                  unsigned short* __restrict__ gobj) {
    __shared__ unsigned short ps[96 * PSP2];
    __shared__ float Rs[96][8];
    __shared__ float invs[96];

    int b = blockIdx.x >> 1, qh = blockIdx.x & 1;
    int t = threadIdx.x, w = t >> 6, lane = t & 63;
    int quad = lane >> 4, lcol = lane & 15;
    int q0 = qh * 96;

    bf16x8 qef[6][2];
#pragma unroll
    for (int mt = 0; mt < 6; ++mt)
#pragma unroll
        for (int ks = 0; ks < 2; ++ks)
            qef[mt][ks] = *(const bf16x8*)(qeb + (q0 + mt * 16 + lcol) * KD_ + ks * 32 + quad * 8);

    f32x4 acc[2][6];
#pragma unroll
    for (int i = 0; i < 2; ++i)
#pragma unroll
        for (int mt = 0; mt < 6; ++mt) acc[i][mt] = (f32x4)(0.f);
    float rsum[6][4];
#pragma unroll
    for (int mt = 0; mt < 6; ++mt)
#pragma unroll
        for (int r = 0; r < 4; ++r) rsum[mt][r] = 0.f;

    const unsigned short* kbB = kbf + (size_t)b * 65536;    // 64 ntile x 2 ks x 512
    const unsigned short* xtB = xtf + (size_t)b * 262144;   // 16 dt x 8 c x 4 ks x 512

    for (int c = 0; c < 8; ++c) {
        // S: wave w covers ntile = c*8 + w (n = c*128 + w*16 + lcol)
        f32x4 s[6];
#pragma unroll
        for (int mt = 0; mt < 6; ++mt) s[mt] = (f32x4)(0.f);
#pragma unroll
        for (int ks = 0; ks < 2; ++ks) {
            bf16x8 bf = *(const bf16x8*)(kbB + (size_t)((c * 8 + w) * 2 + ks) * 512 + lcol * 32 + quad * 8);
#pragma unroll
            for (int mt = 0; mt < 6; ++mt)
                s[mt] = __builtin_amdgcn_mfma_f32_16x16x32_bf16(qef[mt][ks], bf, s[mt], 0, 0, 0);
        }
#pragma unroll
        for (int mt = 0; mt < 6; ++mt)
#pragma unroll
            for (int r = 0; r < 4; ++r) {
                float e = __expf(s[mt][r]);
                s[mt][r] = e;
                rsum[mt][r] += e;
            }
        __syncthreads();   // prior chunk's PV done reading ps
#pragma unroll
        for (int mt = 0; mt < 6; ++mt)
#pragma unroll
            for (int r = 0; r < 4; ++r)
                ps[(mt * 16 + quad * 4 + r) * PSP2 + w * 16 + lcol] = f2bf(s[mt][r]);
        __syncthreads();

        // PV over k = 128 n: wave w owns d-tiles {w, 8+w}
#pragma unroll
        for (int ks = 0; ks < 4; ++ks) {
            bf16x8 af[6];
#pragma unroll
            for (int mt = 0; mt < 6; ++mt)
                af[mt] = *(const bf16x8*)(ps + (mt * 16 + lcol) * PSP2 + ks * 32 + quad * 8);
#pragma unroll
            for (int i = 0; i < 2; ++i) {
                int dt = i * 8 + w;
                bf16x8 bf = *(const bf16x8*)(xtB + (size_t)(((dt * 8 + c) * 4 + ks) * 16 + lcol) * 32 + quad * 8);
#pragma unroll
                for (int mt = 0; mt < 6; ++mt)
                    acc[i][mt] = __builtin_amdgcn_mfma_f32_16x16x32_bf16(af[mt], bf, acc[i][mt], 0, 0, 0);
            }
        }
    }

#pragma unroll
    for (int mt = 0; mt < 6; ++mt)
#pragma unroll
        for (int r = 0; r < 4; ++r) {
            float v = rsum[mt][r];
            v += __shfl_xor(v, 1, 64);
            v += __shfl_xor(v, 2, 64);
            v += __shfl_xor(v, 4, 64);
            v += __shfl_xor(v, 8, 64);
            rsum[mt][r] = v;
        }
    if (lcol == 0) {
#pragma unroll
        for (int mt = 0; mt < 6; ++mt)
#pragma unroll
            for (int r = 0; r < 4; ++r)
                Rs[mt * 16 + quad * 4 + r][w] = rsum[mt][r];
    }
    __syncthreads();
    if (t < 96) {
        float s8 = 0.f;
#pragma unroll
        for (int ww = 0; ww < 8; ++ww) s8 += Rs[t][ww];
        invs[t] = 1.0f / s8;
    }
    __syncthreads();

    unsigned short* gB = gobj + ((size_t)b * Q_ + q0) * D_;
#pragma unroll
    for (int i = 0; i < 2; ++i) {
        int dt = i * 8 + w;
#pragma unroll
        for (int mt = 0; mt < 6; ++mt)
#pragma unroll
            for (int r = 0; r < 4; ++r) {
                int q = mt * 16 + quad * 4 + r;
                gB[q * D_ + dt * 16 + lcol] = f2bf(acc[i][mt][r] * invs[q]);
            }
    }
}

// ---------------------------------------------------------------------------
// rel10: rel7 structure + coalesced Wb loads (verified: 80.4 -> ~62us).
// ---------------------------------------------------------------------------
#define AP4 264

__global__ __launch_bounds__(512, 2)
void rel10_kernel(const unsigned short* __restrict__ gobj,
                  const unsigned short* __restrict__ Wb,
                  const float* __restrict__ coef,
                  float* __restrict__ out) {
    __shared__ unsigned short As[64 * AP4];
    __shared__ float Tp[2048];   // [pgrp(4)][bgl(16)][T1|T2][r(16)]

    int t = threadIdx.x, w = t >> 6, lane = t & 63;
    int quad = lane >> 4, lcol = lane & 15;
    int pgrp = w & 3, rh = w >> 2;          // p-group, r-half
    int bg0 = blockIdx.x * 16;
    int pcol = pgrp * 16 + lcol;

    // zero pad rows (row%4==3): 16 rows x 32 uint4 = 512 stores
    {
        int r3 = t >> 5, c4 = t & 31;
        uint4 zz; zz.x = zz.y = zz.z = zz.w = 0u;
        *(uint4*)(&As[(r3 * 4 + 3) * AP4 + c4 * 8]) = zz;
    }
    // stage 48 gobj rows, row = (j/3)*4 + j%3  (1536 uint4 loads)
#pragma unroll
    for (int i = 0; i < 3; ++i) {
        int idx = i * 512 + t;
        int j = idx >> 5, c4 = idx & 31;
        *(uint4*)(&As[((j / 3) * 4 + (j % 3)) * AP4 + c4 * 8]) =
            *(const uint4*)(gobj + ((size_t)(bg0 * 3 + j)) * 256 + c4 * 8);
    }
    __syncthreads();

    for (int r8 = 0; r8 < 8; ++r8) {
        int r = rh * 8 + r8;
        f32x4 zq[4], zk[4];
#pragma unroll
        for (int mt = 0; mt < 4; ++mt) { zq[mt] = (f32x4)(0.f); zk[mt] = (f32x4)(0.f); }
        // coalesced Wb: contiguous 1KB per wave per (r,kk)
        const unsigned short* bqp = Wb + (size_t)r * 16384 + pcol * 32 + quad * 8;
        const unsigned short* bkp = bqp + (size_t)262144;   // qk=1 plane
#pragma unroll
        for (int kk = 0; kk < 8; ++kk) {
            bf16x8 bq = *(const bf16x8*)(bqp + kk * 2048);
            bf16x8 bk = *(const bf16x8*)(bkp + kk * 2048);
#pragma unroll
            for (int mt = 0; mt < 4; ++mt) {
                bf16x8 a_ = *(const bf16x8*)(&As[(mt * 16 + lcol) * AP4 + kk * 32 + quad * 8]);
                zq[mt] = __builtin_amdgcn_mfma_f32_16x16x32_bf16(a_, bq, zq[mt], 0, 0, 0);
                zk[mt] = __builtin_amdgcn_mfma_f32_16x16x32_bf16(a_, bk, zk[mt], 0, 0, 0);
            }
        }
        // lane holds Z[bgl = mt*4+quad][n = reg][p = pcol]
#pragma unroll
        for (int mt = 0; mt < 4; ++mt) {
            float t1 = zq[mt].x * zk[mt].x + zq[mt].y * zk[mt].y +
                       zq[mt].z * zk[mt].z + zq[mt].w * zk[mt].w;
            float sq = zq[mt].x + zq[mt].y + zq[mt].z + zq[mt].w;
            float sk = zk[mt].x + zk[mt].y + zk[mt].z + zk[mt].w;
            float t2 = sq * sk;
#pragma unroll
            for (int off = 1; off < 16; off <<= 1) {
                t1 += __shfl_xor(t1, off, 64);
                t2 += __shfl_xor(t2, off, 64);
            }
            if (lcol == 0) {
                int bgl = mt * 4 + quad;
                Tp[((pgrp * 16 + bgl) * 2 + 0) * 16 + r] = t1;
                Tp[((pgrp * 16 + bgl) * 2 + 1) * 16 + r] = t2;
            }
        }
    }
    __syncthreads();

    // out[bg][f] = sum_r c1*T1 + c2*T2  (T summed over 4 p-groups)
    int f = t & 63, grp = t >> 6;
#pragma unroll
    for (int i = 0; i < 2; ++i) {
        int bgl = grp * 2 + i;
        float a = 0.f;
#pragma unroll
        for (int r = 0; r < 16; ++r) {
            float T1 = Tp[((0 * 16 + bgl) * 2 + 0) * 16 + r] + Tp[((1 * 16 + bgl) * 2 + 0) * 16 + r] +
                       Tp[((2 * 16 + bgl) * 2 + 0) * 16 + r] + Tp[((3 * 16 + bgl) * 2 + 0) * 16 + r];
            float T2 = Tp[((0 * 16 + bgl) * 2 + 1) * 16 + r] + Tp[((1 * 16 + bgl) * 2 + 1) * 16 + r] +
                       Tp[((2 * 16 + bgl) * 2 + 1) * 16 + r] + Tp[((3 * 16 + bgl) * 2 + 1) * 16 + r];
            a += coef[f * 16 + r] * T1 + coef[1024 + f * 16 + r] * T2;
        }
        out[(size_t)(bg0 + bgl) * NF_ + f] = a;
    }
}

// ---------------------------------------------------------------------------
extern "C" void kernel_launch(void* const* d_in, const int* in_sizes, int n_in,
                              void* d_out, int out_size, void* d_ws, size_t ws_size,
                              hipStream_t stream) {
    const float* x         = (const float*)d_in[0];
    const float* filters   = (const float*)d_in[1];
    const float* query_emb = (const float*)d_in[2];
    const float* Wk_map    = (const float*)d_in[3];
    const float* Wq        = (const float*)d_in[4];
    const float* Wk        = (const float*)d_in[5];
    float* out = (float*)d_out;

    char* p = (char*)d_ws;
    unsigned short* xtf  = (unsigned short*)p;  p += (size_t)B_*D_*N_*2;   // 67.1 MB
    unsigned short* kbf  = (unsigned short*)p;  p += (size_t)B_*N_*KD_*2;  // 16.8 MB
    unsigned short* gobj = (unsigned short*)p;  p += (size_t)B_*Q_*D_*2;   // 12.6 MB
    unsigned short* Wb   = (unsigned short*)p;  p += (size_t)2048*256*2;   //  1.0 MB
    float*          coef = (float*)p;           p += 2048*4;
    unsigned short* qeb  = (unsigned short*)p;  p += (size_t)Q_*KD_*2;
    unsigned short* WkTb = (unsigned short*)p;  p += (size_t)KD_*D_*2;     // 32 KB

    hipLaunchKernelGGL(wkt_kernel, dim3(64), dim3(256), 0, stream,
                       Wk_map, WkTb);
    hipLaunchKernelGGL(xt_kernel, dim3(8, 4, 128), dim3(256), 0, stream,
                       x, xtf);
    hipLaunchKernelGGL(kproj2_kernel, dim3(16, 128), dim3(256), 0, stream,
                       x, WkTb, kbf);
    hipLaunchKernelGGL(qeb_kernel, dim3(48), dim3(256), 0, stream,
                       query_emb, qeb);
    hipLaunchKernelGGL(coef_kernel, dim3(4), dim3(256), 0, stream,
                       filters, coef);
    hipLaunchKernelGGL(wb2_kernel, dim3(32), dim3(256), 0, stream,
                       Wq, Wk, Wb);
    hipLaunchKernelGGL(attn5_kernel, dim3(256), dim3(512), 0, stream,
                       qeb, kbf, xtf, gobj);
    hipLaunchKernelGGL(rel10_kernel, dim3(512), dim3(512), 0, stream,
                       gobj, Wb, coef, out);
}

// Round 8
// 333.854 us; speedup vs baseline: 1.0300x; 1.0300x over previous
//
#include <hip/hip_runtime.h>
#include <math.h>

#define B_   128
#define N_   1024
#define D_   256
#define G_   64
#define GSZ_ 3
#define RD_  16
#define KD_  64
#define PD_  64
#define NF_  64
#define Q_   (G_*GSZ_)   // 192

typedef __attribute__((ext_vector_type(8))) short bf16x8;   // 8 bf16 = 4 VGPRs
typedef __attribute__((ext_vector_type(4))) float f32x4;

__device__ __forceinline__ unsigned short f2bf(float f) {
    unsigned int u = __float_as_uint(f);
    u += 0x7fffu + ((u >> 16) & 1u);       // RNE
    return (unsigned short)(u >> 16);
}

// ---------------------------------------------------------------------------
// coef_kernel: S3-symmetrized filter has 2 DOF per (f,r) (diag / off-diag
// orbit). out = sum_r c1[f,r]*T1[r] + c2[f,r]*T2[r].
// ---------------------------------------------------------------------------
__global__ void coef_kernel(const float* __restrict__ filters,
                            float* __restrict__ coef) {
    int flat = blockIdx.x * 256 + threadIdx.x;
    if (flat >= NF_ * RD_) return;
    int f = flat >> 4, r = flat & 15;
    const float* F = filters + f * 144 + r;
    float diag = F[0] + F[48 + 16] + F[96 + 32];
    float all = 0.f;
#pragma unroll
    for (int u = 0; u < 3; ++u)
#pragma unroll
        for (int v = 0; v < 3; ++v) all += F[u * 48 + v * 16];
    float a = diag * (1.f / 3.f);
    float b = (all - diag) * (1.f / 6.f);
    coef[f * 16 + r] = a - b;
    coef[1024 + f * 16 + r] = b;
}

// ---------------------------------------------------------------------------
// wb2: coalesced layout Wb[qk][r][kk(8)][p(64)][32d] bf16 (verified rel9/
// rel10: -20us on rel). Wave B-frag load = contiguous 1KB burst.
// ---------------------------------------------------------------------------
__global__ __launch_bounds__(256)
void wb2_kernel(const float* __restrict__ Wq,
                const float* __restrict__ Wk,
                unsigned short* __restrict__ Wb) {
    __shared__ unsigned short wt[64 * 264];
    int qk = blockIdx.x >> 4, r = blockIdx.x & 15;
    const float* W = qk ? Wk : Wq;
    int t = threadIdx.x;
#pragma unroll
    for (int i = 0; i < 16; ++i) {
        int flat = i * 256 + t;            // 4096: 256 d x 16 p4
        int d = flat >> 4, p4 = flat & 15;
        float4 v = *(const float4*)(W + ((size_t)r * 256 + d) * 64 + p4 * 4);
        wt[(p4 * 4 + 0) * 264 + d] = f2bf(v.x);
        wt[(p4 * 4 + 1) * 264 + d] = f2bf(v.y);
        wt[(p4 * 4 + 2) * 264 + d] = f2bf(v.z);
        wt[(p4 * 4 + 3) * 264 + d] = f2bf(v.w);
    }
    __syncthreads();
    size_t base = (size_t)(qk * 16 + r) * 16384;
#pragma unroll
    for (int i = 0; i < 8; ++i) {
        int flat = i * 256 + t;            // 2048 uint4: 64 p x 32 segs
        int p = flat >> 5, seg = flat & 31;
        // element (p, d = seg*8) -> [kk = seg>>2][p][d32 = (seg&3)*8]
        *(uint4*)(Wb + base + (size_t)(seg >> 2) * 2048 + p * 32 + (seg & 3) * 8) =
            *(const uint4*)(&wt[p * 264 + seg * 8]);
    }
}

// ---------------------------------------------------------------------------
// qeb_kernel: qeb = bf16(query_emb * beta), beta = 0.125 (exact pow2 scale)
// ---------------------------------------------------------------------------
__global__ void qeb_kernel(const float* __restrict__ qe,
                           unsigned short* __restrict__ qeb) {
    int i = blockIdx.x * 256 + threadIdx.x;
    if (i < Q_ * KD_) qeb[i] = f2bf(qe[i] * 0.125f);
}

// ---------------------------------------------------------------------------
// wkt_kernel: WkTb[kd][d] = bf16(Wk_map[d][kd])  (one-time, 16K elems)
// ---------------------------------------------------------------------------
__global__ void wkt_kernel(const float* __restrict__ Wk_map,
                           unsigned short* __restrict__ WkTb) {
    int i = blockIdx.x * 256 + threadIdx.x;   // [0, 16384)
    int kd = i >> 8, d = i & 255;
    WkTb[kd * 256 + d] = f2bf(Wk_map[d * 64 + kd]);
}

// ---------------------------------------------------------------------------
// xkp_kernel: FUSION of xt + kproj2 (round-7 theory: x was read twice, 134MB
// each pass). One block = (b, 64 n-rows). Stages x tile once into xs (bf16),
// then (a) MFMA k-projection + PE -> kbf (attn-fragment layout) and
// (b) transposed emit -> xtf[b][dt][c][ks][lcol][32].
// xtf-emit addressing: thread t = d-column; per instruction 64 lanes read
// ONE xs row at 64 consecutive d -> conflict-free (a naive column read is
// 8-way conflicted at any 16B-aligned row pitch). Store: 16 lanes (one dt)
// cover 1KB contiguous.
// ---------------------------------------------------------------------------
#define WKP 264   // 256+8 bf16 pad, 16B-aligned rows

__global__ __launch_bounds__(256, 2)
void xkp_kernel(const float* __restrict__ x,
                const unsigned short* __restrict__ WkTb,
                unsigned short* __restrict__ kbf,
                unsigned short* __restrict__ xtf) {
    __shared__ unsigned short wkts[64 * WKP];
    __shared__ unsigned short xs[64 * WKP];
    __shared__ unsigned short Ks[64 * 72];
    int b = blockIdx.y, n0 = blockIdx.x * 64;
    int t = threadIdx.x, w = t >> 6, lane = t & 63;
    int quad = lane >> 4, lcol = lane & 15;

#pragma unroll
    for (int i = 0; i < 8; ++i) {
        int f = i * 256 + t;
        int row = f >> 5, seg = f & 31;
        *(uint4*)(&wkts[row * WKP + seg * 8]) = *(const uint4*)(WkTb + row * 256 + seg * 8);
    }
#pragma unroll
    for (int i = 0; i < 16; ++i) {
        int f = i * 256 + t;
        int row = f >> 6, c4 = f & 63;
        float4 v = *(const float4*)(x + ((size_t)b * N_ + n0 + row) * D_ + c4 * 4);
        uint2 uv;
        uv.x = (unsigned int)f2bf(v.x) | ((unsigned int)f2bf(v.y) << 16);
        uv.y = (unsigned int)f2bf(v.z) | ((unsigned int)f2bf(v.w) << 16);
        *(uint2*)(&xs[row * WKP + c4 * 4]) = uv;
    }
    __syncthreads();

    // ---- k-projection MFMA: C[kd][n] over this block's 64 n ----
    f32x4 z[4];
#pragma unroll
    for (int mt = 0; mt < 4; ++mt) z[mt] = (f32x4)(0.f);
#pragma unroll
    for (int kk = 0; kk < 8; ++kk) {
        bf16x8 bf = *(const bf16x8*)(&xs[(w * 16 + lcol) * WKP + kk * 32 + quad * 8]);
#pragma unroll
        for (int mt = 0; mt < 4; ++mt) {
            bf16x8 af = *(const bf16x8*)(&wkts[(mt * 16 + lcol) * WKP + kk * 32 + quad * 8]);
            z[mt] = __builtin_amdgcn_mfma_f32_16x16x32_bf16(af, bf, z[mt], 0, 0, 0);
        }
    }

    int nl = w * 16 + lcol;
    int n = n0 + nl;
#pragma unroll
    for (int mt = 0; mt < 4; ++mt)
#pragma unroll
        for (int r = 0; r < 4; ++r) {
            int kd = mt * 16 + quad * 4 + r;
            float freq  = expf(-(float)(kd >> 1) * (logf(10000.0f) / 32.0f));
            float angle = (float)n * freq;
            float pe    = (kd & 1) ? cosf(angle) : sinf(angle);
            Ks[nl * 72 + kd] = f2bf(z[mt][r] + pe);
        }

    // ---- xtf emit (independent of Ks; needs only xs) ----
    // thread t = d-column (0..255); iter i = 8-n chunk (0..7)
    {
        int dt = t >> 4, lc = t & 15;
        int c = blockIdx.x >> 1;            // n0 >> 7
        int ks0 = (blockIdx.x & 1) * 2;     // (n0>>5)&3
#pragma unroll
        for (int i = 0; i < 8; ++i) {
            uint4 uv; unsigned short* us = (unsigned short*)&uv;
#pragma unroll
            for (int e = 0; e < 8; ++e)
                us[e] = xs[(i * 8 + e) * WKP + t];
            *(uint4*)(xtf + ((((size_t)b * 16 + dt) * 8 + c) * 4 + ks0 + (i >> 2)) * 512
                            + (size_t)lc * 32 + (i & 3) * 8) = uv;
        }
    }
    __syncthreads();

    // ---- kbf store (attn-fragment layout, unchanged from kproj2) ----
#pragma unroll
    for (int i = 0; i < 2; ++i) {
        int f = i * 256 + t;
        int row = f >> 3, seg = f & 7;       // 64 n-rows x 8 kd-chunks of 8
        int ntile = (n0 >> 4) + (row >> 4), lc = row & 15;
        int ks = seg >> 2, quad8 = (seg & 3) * 8;
        *(uint4*)(kbf + ((size_t)(b * 64 + ntile) * 2 + ks) * 512 + lc * 32 + quad8) =
            *(const uint4*)(&Ks[row * 72 + seg * 8]);
    }
}

// ---------------------------------------------------------------------------
// attn5: both B-operand streams read from fragment-contiguous layouts
// (kbf, xtf); every S and PV B-frag load is a contiguous 1KB burst.
// ---------------------------------------------------------------------------
#define PSP2 136   // 128+8

__global__ __launch_bounds__(512, 2)
void attn5_kernel(const unsigned short* __restrict__ qeb,
                  const unsigned short* __restrict__ kbf,
                  const unsigned short* __restrict__ xtf,
                  unsigned short* __restrict__ gobj) {
    __shared__ unsigned short ps[96 * PSP2];
    __shared__ float Rs[96][8];
    __shared__ float invs[96];

    int b = blockIdx.x >> 1, qh = blockIdx.x & 1;
    int t = threadIdx.x, w = t >> 6, lane = t & 63;
    int quad = lane >> 4, lcol = lane & 15;
    int q0 = qh * 96;

    bf16x8 qef[6][2];
#pragma unroll
    for (int mt = 0; mt < 6; ++mt)
#pragma unroll
        for (int ks = 0; ks < 2; ++ks)
            qef[mt][ks] = *(const bf16x8*)(qeb + (q0 + mt * 16 + lcol) * KD_ + ks * 32 + quad * 8);

    f32x4 acc[2][6];
#pragma unroll
    for (int i = 0; i < 2; ++i)
#pragma unroll
        for (int mt = 0; mt < 6; ++mt) acc[i][mt] = (f32x4)(0.f);
    float rsum[6][4];
#pragma unroll
    for (int mt = 0; mt < 6; ++mt)
#pragma unroll
        for (int r = 0; r < 4; ++r) rsum[mt][r] = 0.f;

    const unsigned short* kbB = kbf + (size_t)b * 65536;    // 64 ntile x 2 ks x 512
    const unsigned short* xtB = xtf + (size_t)b * 262144;   // 16 dt x 8 c x 4 ks x 512

    for (int c = 0; c < 8; ++c) {
        // S: wave w covers ntile = c*8 + w (n = c*128 + w*16 + lcol)
        f32x4 s[6];
#pragma unroll
        for (int mt = 0; mt < 6; ++mt) s[mt] = (f32x4)(0.f);
#pragma unroll
        for (int ks = 0; ks < 2; ++ks) {
            bf16x8 bf = *(const bf16x8*)(kbB + (size_t)((c * 8 + w) * 2 + ks) * 512 + lcol * 32 + quad * 8);
#pragma unroll
            for (int mt = 0; mt < 6; ++mt)
                s[mt] = __builtin_amdgcn_mfma_f32_16x16x32_bf16(qef[mt][ks], bf, s[mt], 0, 0, 0);
        }
#pragma unroll
        for (int mt = 0; mt < 6; ++mt)
#pragma unroll
            for (int r = 0; r < 4; ++r) {
                float e = __expf(s[mt][r]);
                s[mt][r] = e;
                rsum[mt][r] += e;
            }
        __syncthreads();   // prior chunk's PV done reading ps
#pragma unroll
        for (int mt = 0; mt < 6; ++mt)
#pragma unroll
            for (int r = 0; r < 4; ++r)
                ps[(mt * 16 + quad * 4 + r) * PSP2 + w * 16 + lcol] = f2bf(s[mt][r]);
        __syncthreads();

        // PV over k = 128 n: wave w owns d-tiles {w, 8+w}
#pragma unroll
        for (int ks = 0; ks < 4; ++ks) {
            bf16x8 af[6];
#pragma unroll
            for (int mt = 0; mt < 6; ++mt)
                af[mt] = *(const bf16x8*)(ps + (mt * 16 + lcol) * PSP2 + ks * 32 + quad * 8);
#pragma unroll
            for (int i = 0; i < 2; ++i) {
                int dt = i * 8 + w;
                bf16x8 bf = *(const bf16x8*)(xtB + (size_t)(((dt * 8 + c) * 4 + ks) * 16 + lcol) * 32 + quad * 8);
#pragma unroll
                for (int mt = 0; mt < 6; ++mt)
                    acc[i][mt] = __builtin_amdgcn_mfma_f32_16x16x32_bf16(af[mt], bf, acc[i][mt], 0, 0, 0);
            }
        }
    }

#pragma unroll
    for (int mt = 0; mt < 6; ++mt)
#pragma unroll
        for (int r = 0; r < 4; ++r) {
            float v = rsum[mt][r];
            v += __shfl_xor(v, 1, 64);
            v += __shfl_xor(v, 2, 64);
            v += __shfl_xor(v, 4, 64);
            v += __shfl_xor(v, 8, 64);
            rsum[mt][r] = v;
        }
    if (lcol == 0) {
#pragma unroll
        for (int mt = 0; mt < 6; ++mt)
#pragma unroll
            for (int r = 0; r < 4; ++r)
                Rs[mt * 16 + quad * 4 + r][w] = rsum[mt][r];
    }
    __syncthreads();
    if (t < 96) {
        float s8 = 0.f;
#pragma unroll
        for (int ww = 0; ww < 8; ++ww) s8 += Rs[t][ww];
        invs[t] = 1.0f / s8;
    }
    __syncthreads();

    unsigned short* gB = gobj + ((size_t)b * Q_ + q0) * D_;
#pragma unroll
    for (int i = 0; i < 2; ++i) {
        int dt = i * 8 + w;
#pragma unroll
        for (int mt = 0; mt < 6; ++mt)
#pragma unroll
            for (int r = 0; r < 4; ++r) {
                int q = mt * 16 + quad * 4 + r;
                gB[q * D_ + dt * 16 + lcol] = f2bf(acc[i][mt][r] * invs[q]);
            }
    }
}

// ---------------------------------------------------------------------------
// rel10: rel7 structure + coalesced Wb loads (verified: 80.4 -> ~62us).
// ---------------------------------------------------------------------------
#define AP4 264

__global__ __launch_bounds__(512, 2)
void rel10_kernel(const unsigned short* __restrict__ gobj,
                  const unsigned short* __restrict__ Wb,
                  const float* __restrict__ coef,
                  float* __restrict__ out) {
    __shared__ unsigned short As[64 * AP4];
    __shared__ float Tp[2048];   // [pgrp(4)][bgl(16)][T1|T2][r(16)]

    int t = threadIdx.x, w = t >> 6, lane = t & 63;
    int quad = lane >> 4, lcol = lane & 15;
    int pgrp = w & 3, rh = w >> 2;          // p-group, r-half
    int bg0 = blockIdx.x * 16;
    int pcol = pgrp * 16 + lcol;

    // zero pad rows (row%4==3): 16 rows x 32 uint4 = 512 stores
    {
        int r3 = t >> 5, c4 = t & 31;
        uint4 zz; zz.x = zz.y = zz.z = zz.w = 0u;
        *(uint4*)(&As[(r3 * 4 + 3) * AP4 + c4 * 8]) = zz;
    }
    // stage 48 gobj rows, row = (j/3)*4 + j%3  (1536 uint4 loads)
#pragma unroll
    for (int i = 0; i < 3; ++i) {
        int idx = i * 512 + t;
        int j = idx >> 5, c4 = idx & 31;
        *(uint4*)(&As[((j / 3) * 4 + (j % 3)) * AP4 + c4 * 8]) =
            *(const uint4*)(gobj + ((size_t)(bg0 * 3 + j)) * 256 + c4 * 8);
    }
    __syncthreads();

    for (int r8 = 0; r8 < 8; ++r8) {
        int r = rh * 8 + r8;
        f32x4 zq[4], zk[4];
#pragma unroll
        for (int mt = 0; mt < 4; ++mt) { zq[mt] = (f32x4)(0.f); zk[mt] = (f32x4)(0.f); }
        // coalesced Wb: contiguous 1KB per wave per (r,kk)
        const unsigned short* bqp = Wb + (size_t)r * 16384 + pcol * 32 + quad * 8;
        const unsigned short* bkp = bqp + (size_t)262144;   // qk=1 plane
#pragma unroll
        for (int kk = 0; kk < 8; ++kk) {
            bf16x8 bq = *(const bf16x8*)(bqp + kk * 2048);
            bf16x8 bk = *(const bf16x8*)(bkp + kk * 2048);
#pragma unroll
            for (int mt = 0; mt < 4; ++mt) {
                bf16x8 a_ = *(const bf16x8*)(&As[(mt * 16 + lcol) * AP4 + kk * 32 + quad * 8]);
                zq[mt] = __builtin_amdgcn_mfma_f32_16x16x32_bf16(a_, bq, zq[mt], 0, 0, 0);
                zk[mt] = __builtin_amdgcn_mfma_f32_16x16x32_bf16(a_, bk, zk[mt], 0, 0, 0);
            }
        }
        // lane holds Z[bgl = mt*4+quad][n = reg][p = pcol]
#pragma unroll
        for (int mt = 0; mt < 4; ++mt) {
            float t1 = zq[mt].x * zk[mt].x + zq[mt].y * zk[mt].y +
                       zq[mt].z * zk[mt].z + zq[mt].w * zk[mt].w;
            float sq = zq[mt].x + zq[mt].y + zq[mt].z + zq[mt].w;
            float sk = zk[mt].x + zk[mt].y + zk[mt].z + zk[mt].w;
            float t2 = sq * sk;
#pragma unroll
            for (int off = 1; off < 16; off <<= 1) {
                t1 += __shfl_xor(t1, off, 64);
                t2 += __shfl_xor(t2, off, 64);
            }
            if (lcol == 0) {
                int bgl = mt * 4 + quad;
                Tp[((pgrp * 16 + bgl) * 2 + 0) * 16 + r] = t1;
                Tp[((pgrp * 16 + bgl) * 2 + 1) * 16 + r] = t2;
            }
        }
    }
    __syncthreads();

    // out[bg][f] = sum_r c1*T1 + c2*T2  (T summed over 4 p-groups)
    int f = t & 63, grp = t >> 6;
#pragma unroll
    for (int i = 0; i < 2; ++i) {
        int bgl = grp * 2 + i;
        float a = 0.f;
#pragma unroll
        for (int r = 0; r < 16; ++r) {
            float T1 = Tp[((0 * 16 + bgl) * 2 + 0) * 16 + r] + Tp[((1 * 16 + bgl) * 2 + 0) * 16 + r] +
                       Tp[((2 * 16 + bgl) * 2 + 0) * 16 + r] + Tp[((3 * 16 + bgl) * 2 + 0) * 16 + r];
            float T2 = Tp[((0 * 16 + bgl) * 2 + 1) * 16 + r] + Tp[((1 * 16 + bgl) * 2 + 1) * 16 + r] +
                       Tp[((2 * 16 + bgl) * 2 + 1) * 16 + r] + Tp[((3 * 16 + bgl) * 2 + 1) * 16 + r];
            a += coef[f * 16 + r] * T1 + coef[1024 + f * 16 + r] * T2;
        }
        out[(size_t)(bg0 + bgl) * NF_ + f] = a;
    }
}

// ---------------------------------------------------------------------------
extern "C" void kernel_launch(void* const* d_in, const int* in_sizes, int n_in,
                              void* d_out, int out_size, void* d_ws, size_t ws_size,
                              hipStream_t stream) {
    const float* x         = (const float*)d_in[0];
    const float* filters   = (const float*)d_in[1];
    const float* query_emb = (const float*)d_in[2];
    const float* Wk_map    = (const float*)d_in[3];
    const float* Wq        = (const float*)d_in[4];
    const float* Wk        = (const float*)d_in[5];
    float* out = (float*)d_out;

    char* p = (char*)d_ws;
    unsigned short* xtf  = (unsigned short*)p;  p += (size_t)B_*D_*N_*2;   // 67.1 MB
    unsigned short* kbf  = (unsigned short*)p;  p += (size_t)B_*N_*KD_*2;  // 16.8 MB
    unsigned short* gobj = (unsigned short*)p;  p += (size_t)B_*Q_*D_*2;   // 12.6 MB
    unsigned short* Wb   = (unsigned short*)p;  p += (size_t)2048*256*2;   //  1.0 MB
    float*          coef = (float*)p;           p += 2048*4;
    unsigned short* qeb  = (unsigned short*)p;  p += (size_t)Q_*KD_*2;
    unsigned short* WkTb = (unsigned short*)p;  p += (size_t)KD_*D_*2;     // 32 KB

    hipLaunchKernelGGL(wkt_kernel, dim3(64), dim3(256), 0, stream,
                       Wk_map, WkTb);
    hipLaunchKernelGGL(qeb_kernel, dim3(48), dim3(256), 0, stream,
                       query_emb, qeb);
    hipLaunchKernelGGL(coef_kernel, dim3(4), dim3(256), 0, stream,
                       filters, coef);
    hipLaunchKernelGGL(wb2_kernel, dim3(32), dim3(256), 0, stream,
                       Wq, Wk, Wb);
    hipLaunchKernelGGL(xkp_kernel, dim3(16, 128), dim3(256), 0, stream,
                       x, WkTb, kbf, xtf);
    hipLaunchKernelGGL(attn5_kernel, dim3(256), dim3(512), 0, stream,
                       qeb, kbf, xtf, gobj);
    hipLaunchKernelGGL(rel10_kernel, dim3(512), dim3(512), 0, stream,
                       gobj, Wb, coef, out);
}